// Round 10
// baseline (845.483 us; speedup 1.0000x reference)
//
#include <hip/hip_runtime.h>
#include <hip/hip_bf16.h>

typedef __hip_bfloat16 bf16;
typedef __attribute__((ext_vector_type(8))) short short8;
typedef __attribute__((ext_vector_type(4))) float floatx4;

#define NB 16

// drug conv chain:  L 64 ->61(K4,C40) ->56(K6,C80) ->49(K8,C160)
// prot conv chain:  L 1200 ->1197(K4,C40) ->1190(K8,C80) ->1179(K12,C160)

__device__ __forceinline__ float b2f(bf16 x) { return __bfloat162float(x); }
__device__ __forceinline__ float u16bf(unsigned short u) {
    return __uint_as_float(((unsigned)u) << 16);
}
__device__ __forceinline__ unsigned short f2bu(float v) {
    union { bf16 h; unsigned short u; } cv;
    cv.h = __float2bfloat16(v);
    return cv.u;
}

// ---------------- dtype sniffer (R4-proven) ----------------
__global__ void sniff_kernel(const unsigned short* __restrict__ w, int* __restrict__ flag) {
    __shared__ int cnt;
    if (threadIdx.x == 0) cnt = 0;
    __syncthreads();
    int hits = 0;
    for (int s = 0; s < 4; s++) {
        unsigned short u = w[(threadIdx.x * 4 + s) * 2];
        float v = fabsf(u16bf(u));
        if (v > 1e-6f && v < 2.0f) hits++;
    }
    atomicAdd(&cnt, hits);
    __syncthreads();
    if (threadIdx.x == 0) *flag = (cnt > 512) ? 1 : 0;
}

// ---------------- conversions ----------------
// 13 bias segs + 2 zero segs (src=nullptr -> 0.f). grid (490, NSEG).
#define NSEG 15
struct CvtJob {
    const void* src[NSEG];
    float* dst[NSEG];
    int n[NSEG];
};

__global__ void megacvt(CvtJob job, const int* __restrict__ flagp) {
    int seg = blockIdx.y;
    int i = blockIdx.x * 256 + threadIdx.x;
    if (i >= job.n[seg]) return;
    const void* s = job.src[seg];
    if (s == nullptr) { job.dst[seg][i] = 0.f; return; }
    float v = (*flagp) ? b2f(((const bf16*)s)[i]) : ((const float*)s)[i];
    job.dst[seg][i] = v;
}

// embeddings -> bf16 (for conv1 MFMA gather staging)
__global__ void cvt_emb(const void* de, const void* pe, bf16* dB, bf16* pB,
                        const int* __restrict__ flagp) {
    int i = blockIdx.x * 256 + threadIdx.x;
    int f = *flagp;
    if (i < 65 * 64) {
        dB[i] = f ? ((const bf16*)de)[i] : __float2bfloat16(((const float*)de)[i]);
    } else if (i < 65 * 64 + 26 * 64) {
        int j = i - 65 * 64;
        pB[j] = f ? ((const bf16*)pe)[j] : __float2bfloat16(((const float*)pe)[j]);
    }
}

// all six conv-weight MFMA packs in one dispatch: [Cout][CIN][K] -> [k][coP][CIP]
__global__ void pack6(const void* s0, const void* s1, const void* s2,
                      const void* s3, const void* s4, const void* s5,
                      bf16* d0, bf16* d1, bf16* d2, bf16* d3, bf16* d4, bf16* d5,
                      const int* __restrict__ flagp) {
    int y = blockIdx.y;
    const void* src; bf16* dst; int Cout, CIN, K, coP, CIP;
    if (y == 0)      { src = s0; dst = d0; Cout = 40;  CIN = 64; K = 4;  coP = 48;  CIP = 64; }
    else if (y == 1) { src = s1; dst = d1; Cout = 40;  CIN = 64; K = 4;  coP = 48;  CIP = 64; }
    else if (y == 2) { src = s2; dst = d2; Cout = 80;  CIN = 40; K = 6;  coP = 128; CIP = 64; }
    else if (y == 3) { src = s3; dst = d3; Cout = 80;  CIN = 40; K = 8;  coP = 128; CIP = 64; }
    else if (y == 4) { src = s4; dst = d4; Cout = 160; CIN = 80; K = 8;  coP = 192; CIP = 96; }
    else             { src = s5; dst = d5; Cout = 160; CIN = 80; K = 12; coP = 192; CIP = 96; }
    int i = blockIdx.x * 256 + threadIdx.x;
    int total = K * coP * CIP;
    if (i >= total) return;
    int ci = i % CIP;
    int t = i / CIP;
    int co = t % coP;
    int k = t / coP;
    float v = 0.f;
    if (co < Cout && ci < CIN) {
        int s = (co * CIN + ci) * K + k;
        v = (*flagp) ? b2f(((const bf16*)src)[s]) : ((const float*)src)[s];
    }
    dst[i] = __float2bfloat16(v);
}

// [160,160] (o,c) -> bf16 [o][c] (A-operand layout), 3 matrices
__global__ void cvt160b(const void* s0, const void* s1, const void* s2,
                        bf16* d0, bf16* d1, bf16* d2, const int* __restrict__ flagp) {
    int i = blockIdx.x * 256 + threadIdx.x;
    if (i >= 25600) return;
    const void* s = blockIdx.y == 0 ? s0 : (blockIdx.y == 1 ? s1 : s2);
    bf16* d = blockIdx.y == 0 ? d0 : (blockIdx.y == 1 ? d1 : d2);
    float v = (*flagp) ? b2f(((const bf16*)s)[i]) : ((const float*)s)[i];
    d[i] = __float2bfloat16(v);
}

// ---------------- conv via MFMA implicit GEMM (R7-proven) ----------------
template <int K, int CIN, int CHUNKS>
__global__ __launch_bounds__(256) void conv_mfma(const bf16* __restrict__ x,
                                                 const bf16* __restrict__ Wp,
                                                 const float* __restrict__ bias,
                                                 bf16* __restrict__ y,
                                                 int Lin, int Lout, int Cout,
                                                 int coP, int tilesL) {
    const int CIP = CHUNKS * 32;
    const int PCI = CIP + 8;
    const int TLX = 64 + K - 1;
    __shared__ __align__(16) unsigned short xT[TLX * PCI];
    int b = blockIdx.x / tilesL;
    int l0 = (blockIdx.x % tilesL) << 6;
    const unsigned short* xb = (const unsigned short*)x + (size_t)b * CIN * Lin;
    for (int i = threadIdx.x; i < TLX * CIP; i += 256) {
        int ci = i / TLX, l = i - ci * TLX;
        unsigned short v = 0;
        int gl = l0 + l;
        if (ci < CIN && gl < Lin) v = xb[ci * Lin + gl];
        xT[l * PCI + ci] = v;
    }
    __syncthreads();
    int lane = threadIdx.x & 63;
    int w = threadIdx.x >> 6;
    int ct = blockIdx.y * 4 + w;
    int n = lane & 15, quad = lane >> 4;
    floatx4 acc[4];
#pragma unroll
    for (int i = 0; i < 4; i++) acc[i] = (floatx4){0.f, 0.f, 0.f, 0.f};
    const unsigned short* wbase = (const unsigned short*)Wp;
#pragma unroll
    for (int k = 0; k < K; k++) {
#pragma unroll
        for (int ch = 0; ch < CHUNKS; ch++) {
            short8 a = *(const short8*)(wbase +
                        ((size_t)(k * coP + ct * 16 + n)) * CIP + ch * 32 + quad * 8);
#pragma unroll
            for (int nt = 0; nt < 4; nt++) {
                short8 bb = *(const short8*)(xT + (nt * 16 + n + k) * PCI + ch * 32 + quad * 8);
                acc[nt] = __builtin_amdgcn_mfma_f32_16x16x32_bf16(a, bb, acc[nt], 0, 0, 0);
            }
        }
    }
    int m0 = quad * 4;
#pragma unroll
    for (int nt = 0; nt < 4; nt++) {
        int l = l0 + nt * 16 + n;
        if (l >= Lout) continue;
#pragma unroll
        for (int r = 0; r < 4; r++) {
            int co = ct * 16 + m0 + r;
            if (co < Cout)
                y[((size_t)b * Cout + co) * Lout + l] =
                    __float2bfloat16(fmaxf(acc[nt][r] + bias[co], 0.f));
        }
    }
}

// ---------------- conv1 via MFMA with embedding-gather staging ----------------
// K=4, CIN=64 (2 chunks), Cout=40, coP=48 (3 wave-tiles; wave 3 idle).
__global__ __launch_bounds__(256) void conv1_mfma(const int* __restrict__ dtok,
                                                  const int* __restrict__ ptok,
                                                  const bf16* __restrict__ embDB,
                                                  const bf16* __restrict__ embPB,
                                                  const bf16* __restrict__ dW1p,
                                                  const bf16* __restrict__ pW1p,
                                                  const float* __restrict__ db1f,
                                                  const float* __restrict__ pb1f,
                                                  bf16* __restrict__ d1,
                                                  bf16* __restrict__ p1) {
    const int K = 4, CIP = 64, PCI = 72, TLX = 67, coP = 48, Cout = 40;
    __shared__ __align__(16) unsigned short xT[TLX * PCI];
    __shared__ int stok[TLX];
    bool isD = blockIdx.x < 16;
    int b, l0, Lin, Lout;
    const int* tok; const unsigned short* embB; const unsigned short* Wp;
    const float* bias; bf16* y;
    if (isD) {
        b = blockIdx.x; l0 = 0; Lin = 64; Lout = 61;
        tok = dtok; embB = (const unsigned short*)embDB;
        Wp = (const unsigned short*)dW1p; bias = db1f; y = d1;
    } else {
        int bx = blockIdx.x - 16;
        b = bx / 19; l0 = (bx % 19) << 6; Lin = 1200; Lout = 1197;
        tok = ptok; embB = (const unsigned short*)embPB;
        Wp = (const unsigned short*)pW1p; bias = pb1f; y = p1;
    }
    if (threadIdx.x < TLX) {
        int l = l0 + threadIdx.x;
        stok[threadIdx.x] = (l < Lin) ? tok[b * Lin + l] : -1;
    }
    __syncthreads();
    for (int i = threadIdx.x; i < TLX * CIP; i += 256) {
        int ci = i / TLX, l = i - ci * TLX;
        int t = stok[l];
        xT[l * PCI + ci] = (t >= 0) ? embB[t * 64 + ci] : (unsigned short)0;
    }
    __syncthreads();
    int lane = threadIdx.x & 63;
    int w = threadIdx.x >> 6;
    int n = lane & 15, quad = lane >> 4;
    if (w >= 3) return;
    floatx4 acc[4];
#pragma unroll
    for (int i = 0; i < 4; i++) acc[i] = (floatx4){0.f, 0.f, 0.f, 0.f};
#pragma unroll
    for (int k = 0; k < K; k++) {
#pragma unroll
        for (int ch = 0; ch < 2; ch++) {
            short8 a = *(const short8*)(Wp +
                        ((size_t)(k * coP + w * 16 + n)) * CIP + ch * 32 + quad * 8);
#pragma unroll
            for (int nt = 0; nt < 4; nt++) {
                short8 bb = *(const short8*)(xT + (nt * 16 + n + k) * PCI + ch * 32 + quad * 8);
                acc[nt] = __builtin_amdgcn_mfma_f32_16x16x32_bf16(a, bb, acc[nt], 0, 0, 0);
            }
        }
    }
    int m0 = quad * 4;
#pragma unroll
    for (int nt = 0; nt < 4; nt++) {
        int l = l0 + nt * 16 + n;
        if (l >= Lout) continue;
#pragma unroll
        for (int r = 0; r < 4; r++) {
            int co = w * 16 + m0 + r;
            if (co < Cout)
                y[((size_t)b * Cout + co) * Lout + l] =
                    __float2bfloat16(fmaxf(acc[nt][r] + bias[co], 0.f));
        }
    }
}

// ---------------- attention projection via MFMA (R8-proven) ----------------
__global__ __launch_bounds__(256) void att_proj_mfma(const bf16* __restrict__ dcB,
                                                     const bf16* __restrict__ pcB,
                                                     const bf16* __restrict__ dWB,
                                                     const bf16* __restrict__ pWB,
                                                     const float* __restrict__ dbF,
                                                     const float* __restrict__ pbF,
                                                     float* __restrict__ datt,
                                                     bf16* __restrict__ pattB) {
    const int PCI = 168;
    __shared__ __align__(16) unsigned short xT[64 * PCI];
    bool isD = blockIdx.x < 16;
    int b, l0, L;
    const unsigned short* xsrc; const unsigned short* W; const float* bias;
    if (isD) {
        b = blockIdx.x; l0 = 0; L = 49;
        xsrc = (const unsigned short*)dcB; W = (const unsigned short*)dWB; bias = dbF;
    } else {
        int bx = blockIdx.x - 16;
        b = bx / 19; l0 = (bx % 19) << 6; L = 1179;
        xsrc = (const unsigned short*)pcB; W = (const unsigned short*)pWB; bias = pbF;
    }
    const unsigned short* xb = xsrc + (size_t)b * 160 * L;
    for (int i = threadIdx.x; i < 160 * 64; i += 256) {
        int c = i >> 6, j = i & 63;
        int l = l0 + j;
        xT[j * PCI + c] = (l < L) ? xb[(size_t)c * L + l] : (unsigned short)0;
    }
    __syncthreads();
    int lane = threadIdx.x & 63;
    int w = threadIdx.x >> 6;
    int t = blockIdx.y * 4 + w;
    int n = lane & 15, quad = lane >> 4;
    if (t >= 10) return;
    floatx4 acc[4];
#pragma unroll
    for (int i = 0; i < 4; i++) acc[i] = (floatx4){0.f, 0.f, 0.f, 0.f};
#pragma unroll
    for (int ch = 0; ch < 5; ch++) {
        short8 a = *(const short8*)(W + ((size_t)(t * 16 + n)) * 160 + ch * 32 + quad * 8);
#pragma unroll
        for (int nt = 0; nt < 4; nt++) {
            short8 bb = *(const short8*)(xT + (nt * 16 + n) * PCI + ch * 32 + quad * 8);
            acc[nt] = __builtin_amdgcn_mfma_f32_16x16x32_bf16(a, bb, acc[nt], 0, 0, 0);
        }
    }
    int m0 = quad * 4;
    int o0 = t * 16 + m0;
#pragma unroll
    for (int nt = 0; nt < 4; nt++) {
        int l = l0 + nt * 16 + n;
        if (l >= L) continue;
        if (isD) {
            float4 v;
            v.x = acc[nt][0] + bias[o0 + 0];
            v.y = acc[nt][1] + bias[o0 + 1];
            v.z = acc[nt][2] + bias[o0 + 2];
            v.w = acc[nt][3] + bias[o0 + 3];
            *(float4*)(datt + ((size_t)b * 49 + l) * 160 + o0) = v;
        } else {
            ushort4 u;
            u.x = f2bu(acc[nt][0] + bias[o0 + 0]);
            u.y = f2bu(acc[nt][1] + bias[o0 + 1]);
            u.z = f2bu(acc[nt][2] + bias[o0 + 2]);
            u.w = f2bu(acc[nt][3] + bias[o0 + 3]);
            *(ushort4*)((unsigned short*)pattB + ((size_t)b * 1179 + l) * 160 + o0) = u;
        }
    }
}

// ---------------- fused means v2: relu identity + d-chunking (no spills) ----------------
// relu(x) = 0.5*(x+|x|):  Mp[p] = (Sd + 49*pv + A_p)/98 ; Md_part[d] = (np*dv + Sp + B_d)/2.
// Invalid p use pv=0; B_d corrected by (32-np)*|dv| exactly.
template <int DC>
__device__ __forceinline__ void mean_chunk(int c0, int b, int k, int np,
                                           const float* __restrict__ datt,
                                           const unsigned short* __restrict__ pb, int p0,
                                           float Sp, float* __restrict__ A,
                                           float& Sd, float* __restrict__ Md) {
    float dv[DC], Bd[DC];
#pragma unroll
    for (int d = 0; d < DC; d++) {
        dv[d] = datt[((size_t)b * 49 + c0 + d) * 160 + k];
        Bd[d] = 0.f;
        Sd += dv[d];
    }
#pragma unroll
    for (int pi = 0; pi < 32; pi++) {
        int p = p0 + pi;
        float pv = (p < 1179) ? u16bf(pb[(size_t)p * 160]) : 0.f;
        float Ap = 0.f;
#pragma unroll
        for (int d = 0; d < DC; d++) {
            float t = dv[d] + pv;
            float at = __builtin_fabsf(t);
            Ap += at;
            Bd[d] += at;
        }
        A[pi] += Ap;
    }
    float corr = (float)(32 - np);
    float fnp = (float)np;
#pragma unroll
    for (int d = 0; d < DC; d++) {
        float bd = Bd[d] - corr * __builtin_fabsf(dv[d]);
        atomicAdd(Md + ((size_t)b * 49 + c0 + d) * 160 + k,
                  0.5f * (fnp * dv[d] + Sp + bd));
    }
}

__global__ __launch_bounds__(192) void mean_fused(const float* __restrict__ datt,
                                                  const bf16* __restrict__ patt,
                                                  bf16* __restrict__ MpW,
                                                  float* __restrict__ Md) {
    int k = threadIdx.x;
    if (k >= 160) return;
    int b = blockIdx.x / 37;
    int p0 = (blockIdx.x % 37) * 32;
    int np = min(32, 1179 - p0);
    const unsigned short* pb = (const unsigned short*)patt + (size_t)b * 1179 * 160 + k;
    float Sp = 0.f;
#pragma unroll
    for (int pi = 0; pi < 32; pi++) {
        int p = p0 + pi;
        Sp += (p < 1179) ? u16bf(pb[(size_t)p * 160]) : 0.f;
    }
    float A[32];
#pragma unroll
    for (int i = 0; i < 32; i++) A[i] = 0.f;
    float Sd = 0.f;
    mean_chunk<13>(0, b, k, np, datt, pb, p0, Sp, A, Sd, Md);
    mean_chunk<12>(13, b, k, np, datt, pb, p0, Sp, A, Sd, Md);
    mean_chunk<12>(25, b, k, np, datt, pb, p0, Sp, A, Sd, Md);
    mean_chunk<12>(37, b, k, np, datt, pb, p0, Sp, A, Sd, Md);
#pragma unroll
    for (int pi = 0; pi < 32; pi++) {
        int p = p0 + pi;
        if (p < 1179) {
            float pv = u16bf(pb[(size_t)p * 160]);
            float s = 0.5f * (Sd + 49.f * pv + A[pi]) * (1.f / 49.f);
            MpW[((size_t)b * 1184 + p) * 160 + k] = __float2bfloat16(s);
        }
    }
}

// ---------------- att_sig via MFMA + fused sigmoid/scale/maxpool (R8-proven) ----------------
__global__ __launch_bounds__(256) void att_sig_mfma(const float* __restrict__ Md,
                                                    const bf16* __restrict__ MpW,
                                                    const bf16* __restrict__ wattB,
                                                    const float* __restrict__ attbF,
                                                    const bf16* __restrict__ dcB,
                                                    const bf16* __restrict__ pcB,
                                                    float* __restrict__ pair) {
    const int PCI = 168;
    __shared__ __align__(16) unsigned short sM[64 * PCI];
    bool isD = blockIdx.x < 16;
    int b, p0, L, off;
    const unsigned short* conv;
    if (isD) {
        b = blockIdx.x; p0 = 0; L = 49; off = 0; conv = (const unsigned short*)dcB;
        for (int i = threadIdx.x; i < 160 * 64; i += 256) {
            int r = i / 160, k = i - r * 160;
            float v = (r < 49) ? Md[((size_t)b * 49 + r) * 160 + k] * (1.f / 1179.f) : 0.f;
            sM[r * PCI + k] = f2bu(v);
        }
    } else {
        int bx = blockIdx.x - 16;
        b = bx / 19; p0 = (bx % 19) << 6; L = 1179; off = 160;
        conv = (const unsigned short*)pcB;
        const unsigned short* mb = (const unsigned short*)MpW + (size_t)b * 1184 * 160;
        for (int i = threadIdx.x; i < 160 * 64; i += 256) {
            int r = i / 160, k = i - r * 160;
            int p = p0 + r;
            sM[r * PCI + k] = (p < 1179) ? mb[(size_t)p * 160 + k] : (unsigned short)0;
        }
    }
    __syncthreads();
    int lane = threadIdx.x & 63;
    int w = threadIdx.x >> 6;
    int t = blockIdx.y * 4 + w;
    int n = lane & 15, quad = lane >> 4;
    if (t >= 10) return;
    floatx4 acc[4];
#pragma unroll
    for (int i = 0; i < 4; i++) acc[i] = (floatx4){0.f, 0.f, 0.f, 0.f};
    const unsigned short* W = (const unsigned short*)wattB;
#pragma unroll
    for (int ch = 0; ch < 5; ch++) {
        short8 a = *(const short8*)(W + ((size_t)(t * 16 + n)) * 160 + ch * 32 + quad * 8);
#pragma unroll
        for (int nt = 0; nt < 4; nt++) {
            short8 bb = *(const short8*)(sM + (nt * 16 + n) * PCI + ch * 32 + quad * 8);
            acc[nt] = __builtin_amdgcn_mfma_f32_16x16x32_bf16(a, bb, acc[nt], 0, 0, 0);
        }
    }
    int m0 = quad * 4;
    float vmax[4] = {0.f, 0.f, 0.f, 0.f};
#pragma unroll
    for (int nt = 0; nt < 4; nt++) {
        int p = p0 + nt * 16 + n;
#pragma unroll
        for (int r = 0; r < 4; r++) {
            int o = t * 16 + m0 + r;
            float sig = 1.f / (1.f + __expf(-(acc[nt][r] + attbF[o])));
            float v = 0.f;
            if (p < L) v = u16bf(conv[((size_t)b * 160 + o) * L + p]) * (0.5f + sig);
            vmax[r] = fmaxf(vmax[r], v);
        }
    }
#pragma unroll
    for (int m = 1; m < 16; m <<= 1) {
#pragma unroll
        for (int r = 0; r < 4; r++)
            vmax[r] = fmaxf(vmax[r], __shfl_xor(vmax[r], m, 64));
    }
    if (n == 0) {
#pragma unroll
        for (int r = 0; r < 4; r++)
            atomicMax((unsigned int*)(pair + b * 320 + off + t * 16 + m0 + r),
                      __float_as_uint(vmax[r]));
    }
}

// ---------------- MLP: block-per-output GEMV (R9-proven) ----------------
__global__ __launch_bounds__(256) void fc_block(const float* __restrict__ in,
                                                const void* __restrict__ W,
                                                const float* __restrict__ bias,
                                                float* __restrict__ out,
                                                int IN, int OUT,
                                                const int* __restrict__ flagp) {
    int j = blockIdx.x;
    int w = threadIdx.x >> 6, li = threadIdx.x & 63;
    int nv = IN >> 2;
    const float4* i0 = (const float4*)(in + (size_t)(w * 4 + 0) * IN);
    const float4* i1 = (const float4*)(in + (size_t)(w * 4 + 1) * IN);
    const float4* i2 = (const float4*)(in + (size_t)(w * 4 + 2) * IN);
    const float4* i3 = (const float4*)(in + (size_t)(w * 4 + 3) * IN);
    float p0 = 0.f, p1 = 0.f, p2 = 0.f, p3 = 0.f;
    if (*flagp) {
        const ushort4* w4 = (const ushort4*)((const unsigned short*)W + (size_t)j * IN);
        for (int v = li; v < nv; v += 64) {
            ushort4 u = w4[v];
            float wa = u16bf(u.x), wb = u16bf(u.y), wc = u16bf(u.z), wd = u16bf(u.w);
            float4 x;
            x = i0[v]; p0 += x.x * wa + x.y * wb + x.z * wc + x.w * wd;
            x = i1[v]; p1 += x.x * wa + x.y * wb + x.z * wc + x.w * wd;
            x = i2[v]; p2 += x.x * wa + x.y * wb + x.z * wc + x.w * wd;
            x = i3[v]; p3 += x.x * wa + x.y * wb + x.z * wc + x.w * wd;
        }
    } else {
        const float4* w4 = (const float4*)((const float*)W + (size_t)j * IN);
        for (int v = li; v < nv; v += 64) {
            float4 u = w4[v];
            float4 x;
            x = i0[v]; p0 += x.x * u.x + x.y * u.y + x.z * u.z + x.w * u.w;
            x = i1[v]; p1 += x.x * u.x + x.y * u.y + x.z * u.z + x.w * u.w;
            x = i2[v]; p2 += x.x * u.x + x.y * u.y + x.z * u.z + x.w * u.w;
            x = i3[v]; p3 += x.x * u.x + x.y * u.y + x.z * u.z + x.w * u.w;
        }
    }
#pragma unroll
    for (int m = 1; m < 64; m <<= 1) {
        p0 += __shfl_xor(p0, m, 64);
        p1 += __shfl_xor(p1, m, 64);
        p2 += __shfl_xor(p2, m, 64);
        p3 += __shfl_xor(p3, m, 64);
    }
    if (li == 0) {
        float bj = bias[j];
        float o0 = p0 + bj, o1 = p1 + bj, o2 = p2 + bj, o3 = p3 + bj;
        o0 = o0 > 0.f ? o0 : 0.01f * o0;
        o1 = o1 > 0.f ? o1 : 0.01f * o1;
        o2 = o2 > 0.f ? o2 : 0.01f * o2;
        o3 = o3 > 0.f ? o3 : 0.01f * o3;
        out[(size_t)(w * 4 + 0) * OUT + j] = o0;
        out[(size_t)(w * 4 + 1) * OUT + j] = o1;
        out[(size_t)(w * 4 + 2) * OUT + j] = o2;
        out[(size_t)(w * 4 + 3) * OUT + j] = o3;
    }
}

__global__ __launch_bounds__(256) void out_block(const float* __restrict__ h,
                                                 const void* __restrict__ W,
                                                 const float* __restrict__ biasF,
                                                 void* __restrict__ out,
                                                 const int* __restrict__ flagp) {
    int j = blockIdx.x;
    int w = threadIdx.x >> 6, li = threadIdx.x & 63;
    const int IN = 512, nv = 128;
    const float4* i0 = (const float4*)(h + (size_t)(w * 4 + 0) * IN);
    const float4* i1 = (const float4*)(h + (size_t)(w * 4 + 1) * IN);
    const float4* i2 = (const float4*)(h + (size_t)(w * 4 + 2) * IN);
    const float4* i3 = (const float4*)(h + (size_t)(w * 4 + 3) * IN);
    float p0 = 0.f, p1 = 0.f, p2 = 0.f, p3 = 0.f;
    int flag = *flagp;
    if (flag) {
        const ushort4* w4 = (const ushort4*)((const unsigned short*)W + (size_t)j * IN);
        for (int v = li; v < nv; v += 64) {
            ushort4 u = w4[v];
            float wa = u16bf(u.x), wb = u16bf(u.y), wc = u16bf(u.z), wd = u16bf(u.w);
            float4 x;
            x = i0[v]; p0 += x.x * wa + x.y * wb + x.z * wc + x.w * wd;
            x = i1[v]; p1 += x.x * wa + x.y * wb + x.z * wc + x.w * wd;
            x = i2[v]; p2 += x.x * wa + x.y * wb + x.z * wc + x.w * wd;
            x = i3[v]; p3 += x.x * wa + x.y * wb + x.z * wc + x.w * wd;
        }
    } else {
        const float4* w4 = (const float4*)((const float*)W + (size_t)j * IN);
        for (int v = li; v < nv; v += 64) {
            float4 u = w4[v];
            float4 x;
            x = i0[v]; p0 += x.x * u.x + x.y * u.y + x.z * u.z + x.w * u.w;
            x = i1[v]; p1 += x.x * u.x + x.y * u.y + x.z * u.z + x.w * u.w;
            x = i2[v]; p2 += x.x * u.x + x.y * u.y + x.z * u.z + x.w * u.w;
            x = i3[v]; p3 += x.x * u.x + x.y * u.y + x.z * u.z + x.w * u.w;
        }
    }
#pragma unroll
    for (int m = 1; m < 64; m <<= 1) {
        p0 += __shfl_xor(p0, m, 64);
        p1 += __shfl_xor(p1, m, 64);
        p2 += __shfl_xor(p2, m, 64);
        p3 += __shfl_xor(p3, m, 64);
    }
    if (li == 0) {
        float bj = biasF[j];
        float o0 = p0 + bj, o1 = p1 + bj, o2 = p2 + bj, o3 = p3 + bj;
        if (flag) {
            bf16* ob = (bf16*)out;
            ob[(w * 4 + 0) * 2 + j] = __float2bfloat16(o0);
            ob[(w * 4 + 1) * 2 + j] = __float2bfloat16(o1);
            ob[(w * 4 + 2) * 2 + j] = __float2bfloat16(o2);
            ob[(w * 4 + 3) * 2 + j] = __float2bfloat16(o3);
        } else {
            float* of = (float*)out;
            of[(w * 4 + 0) * 2 + j] = o0;
            of[(w * 4 + 1) * 2 + j] = o1;
            of[(w * 4 + 2) * 2 + j] = o2;
            of[(w * 4 + 3) * 2 + j] = o3;
        }
    }
}

extern "C" void kernel_launch(void* const* d_in, const int* in_sizes, int n_in,
                              void* d_out, int out_size, void* d_ws, size_t ws_size,
                              hipStream_t stream) {
    const int* drug_tok = (const int*)d_in[0];
    const int* prot_tok = (const int*)d_in[1];
    const void* drug_emb = d_in[2];
    const void* prot_emb = d_in[3];
    const void* dW1 = d_in[4];  const void* db1 = d_in[5];
    const void* dW2 = d_in[6];  const void* db2 = d_in[7];
    const void* dW3 = d_in[8];  const void* db3 = d_in[9];
    const void* pW1 = d_in[10]; const void* pb1 = d_in[11];
    const void* pW2 = d_in[12]; const void* pb2 = d_in[13];
    const void* pW3 = d_in[14]; const void* pb3 = d_in[15];
    const void* dattW = d_in[16]; const void* dattb = d_in[17];
    const void* pattW = d_in[18]; const void* pattb = d_in[19];
    const void* attW  = d_in[20]; const void* attb  = d_in[21];
    const void* fc1W = d_in[22]; const void* fc1b = d_in[23];
    const void* fc2W = d_in[24]; const void* fc2b = d_in[25];
    const void* fc3W = d_in[26]; const void* fc3b = d_in[27];
    const void* outW = d_in[28]; const void* outb = d_in[29];

    char* base = (char*)d_ws;
    size_t cur = 0;
    auto alloc = [&](size_t bytes) -> char* {
        char* p = base + cur;
        cur = (cur + bytes + 255) & ~(size_t)255;
        return p;
    };
    int*   flag  = (int*)alloc(256);
    bf16* embDB = (bf16*)alloc(65 * 64 * 2);
    bf16* embPB = (bf16*)alloc(26 * 64 * 2);
    bf16* dW1p = (bf16*)alloc((size_t)4 * 48 * 64 * 2);
    bf16* pW1p = (bf16*)alloc((size_t)4 * 48 * 64 * 2);
    bf16* dW2p = (bf16*)alloc((size_t)6 * 128 * 64 * 2);
    bf16* dW3p = (bf16*)alloc((size_t)8 * 192 * 96 * 2);
    bf16* pW2p = (bf16*)alloc((size_t)8 * 128 * 64 * 2);
    bf16* pW3p = (bf16*)alloc((size_t)12 * 192 * 96 * 2);
    float* db1f = (float*)alloc(40 * 4);
    float* db2f = (float*)alloc(80 * 4);
    float* db3f = (float*)alloc(160 * 4);
    float* pb1f = (float*)alloc(40 * 4);
    float* pb2f = (float*)alloc(80 * 4);
    float* pb3f = (float*)alloc(160 * 4);
    float* dattbF = (float*)alloc(160 * 4);
    float* pattbF = (float*)alloc(160 * 4);
    float* attbF  = (float*)alloc(160 * 4);
    float* fc1bF = (float*)alloc(1024 * 4);
    float* fc2bF = (float*)alloc(1024 * 4);
    float* fc3bF = (float*)alloc(512 * 4);
    float* outbF = (float*)alloc(2 * 4);
    bf16* dattWB = (bf16*)alloc(25600 * 2);
    bf16* pattWB = (bf16*)alloc(25600 * 2);
    bf16* wattB  = (bf16*)alloc(25600 * 2);
    bf16* d1  = (bf16*)alloc((size_t)NB * 40 * 61 * 2);
    bf16* d2  = (bf16*)alloc((size_t)NB * 80 * 56 * 2);
    bf16* dcB = (bf16*)alloc((size_t)NB * 160 * 49 * 2);
    bf16* p1  = (bf16*)alloc((size_t)NB * 40 * 1197 * 2);
    bf16* p2  = (bf16*)alloc((size_t)NB * 80 * 1190 * 2);
    bf16* pcB = (bf16*)alloc((size_t)NB * 160 * 1179 * 2);
    float* datt  = (float*)alloc((size_t)NB * 49 * 160 * 4);
    bf16* pattB = (bf16*)alloc((size_t)NB * 1179 * 160 * 2);
    float* Md   = (float*)alloc((size_t)NB * 49 * 160 * 4);
    bf16* MpW  = (bf16*)alloc((size_t)NB * 1184 * 160 * 2);
    float* pair = (float*)alloc(NB * 320 * 4);
    float* h1 = (float*)alloc(NB * 1024 * 4);
    float* h2 = (float*)alloc(NB * 1024 * 4);
    float* h3 = (float*)alloc(NB * 512 * 4);

    // 1) dtype sniff
    sniff_kernel<<<1, 256, 0, stream>>>((const unsigned short*)fc2W, flag);

    // 2) parameter conversion (13 bias segs + pair/Md zero segs)
    CvtJob job;
    int si = 0;
    auto add = [&](const void* s, float* d, int n) { job.src[si] = s; job.dst[si] = d; job.n[si] = n; si++; };
    add(db1, db1f, 40); add(db2, db2f, 80); add(db3, db3f, 160);
    add(pb1, pb1f, 40); add(pb2, pb2f, 80); add(pb3, pb3f, 160);
    add(dattb, dattbF, 160); add(pattb, pattbF, 160); add(attb, attbF, 160);
    add(fc1b, fc1bF, 1024); add(fc2b, fc2bF, 1024); add(fc3b, fc3bF, 512);
    add(outb, outbF, 2);
    add(nullptr, pair, NB * 320);
    add(nullptr, Md, NB * 49 * 160);
    megacvt<<<dim3(490, NSEG), 256, 0, stream>>>(job, flag);
    cvt_emb<<<23, 256, 0, stream>>>(drug_emb, prot_emb, embDB, embPB, flag);
    pack6<<<dim3(864, 6), 256, 0, stream>>>(dW1, pW1, dW2, pW2, dW3, pW3,
                                            dW1p, pW1p, dW2p, pW2p, dW3p, pW3p, flag);
    cvt160b<<<dim3(100, 3), 256, 0, stream>>>(dattW, pattW, attW, dattWB, pattWB, wattB, flag);

    // 3) CNN stacks: all MFMA now
    conv1_mfma<<<16 + 16 * 19, 256, 0, stream>>>(drug_tok, prot_tok, embDB, embPB,
                                                 dW1p, pW1p, db1f, pb1f, d1, p1);
    conv_mfma<6, 40, 2><<<dim3(16, 2), 256, 0, stream>>>(d1, dW2p, db2f, d2, 61, 56, 80, 128, 1);
    conv_mfma<8, 40, 2><<<dim3(16 * 19, 2), 256, 0, stream>>>(p1, pW2p, pb2f, p2, 1197, 1190, 80, 128, 19);
    conv_mfma<8, 80, 3><<<dim3(16, 3), 256, 0, stream>>>(d2, dW3p, db3f, dcB, 56, 49, 160, 192, 1);
    conv_mfma<12, 80, 3><<<dim3(16 * 19, 3), 256, 0, stream>>>(p2, pW3p, pb3f, pcB, 1190, 1179, 160, 192, 19);

    // 4) attention projections (MFMA)
    att_proj_mfma<<<dim3(16 + 304, 3), 256, 0, stream>>>(dcB, pcB, dattWB, pattWB,
                                                         dattbF, pattbF, datt, pattB);

    // 5) fused pairwise relu-means (relu-identity, register-chunked)
    mean_fused<<<16 * 37, 192, 0, stream>>>(datt, pattB, MpW, Md);

    // 6) fused attW-GEMM + sigmoid + scale + maxpool (MFMA)
    att_sig_mfma<<<dim3(16 + 304, 3), 256, 0, stream>>>(Md, MpW, wattB, attbF, dcB, pcB, pair);

    // 7) MLP head (block-per-output GEMV)
    fc_block<<<1024, 256, 0, stream>>>(pair, fc1W, fc1bF, h1, 320, 1024, flag);
    fc_block<<<1024, 256, 0, stream>>>(h1, fc2W, fc2bF, h2, 1024, 1024, flag);
    fc_block<<<512, 256, 0, stream>>>(h2, fc3W, fc3bF, h3, 1024, 512, flag);
    out_block<<<2, 256, 0, stream>>>(h3, outW, outbF, d_out, flag);
}

// Round 11
// 296.243 us; speedup vs baseline: 2.8540x; 2.8540x over previous
//
#include <hip/hip_runtime.h>
#include <hip/hip_bf16.h>

typedef __hip_bfloat16 bf16;
typedef __attribute__((ext_vector_type(8))) short short8;
typedef __attribute__((ext_vector_type(4))) float floatx4;

#define NB 16

// drug conv chain:  L 64 ->61(K4,C40) ->56(K6,C80) ->49(K8,C160)
// prot conv chain:  L 1200 ->1197(K4,C40) ->1190(K8,C80) ->1179(K12,C160)

__device__ __forceinline__ float b2f(bf16 x) { return __bfloat162float(x); }
__device__ __forceinline__ float u16bf(unsigned short u) {
    return __uint_as_float(((unsigned)u) << 16);
}
__device__ __forceinline__ unsigned short f2bu(float v) {
    union { bf16 h; unsigned short u; } cv;
    cv.h = __float2bfloat16(v);
    return cv.u;
}

// ---------------- dtype sniffer (R4-proven) ----------------
__global__ void sniff_kernel(const unsigned short* __restrict__ w, int* __restrict__ flag) {
    __shared__ int cnt;
    if (threadIdx.x == 0) cnt = 0;
    __syncthreads();
    int hits = 0;
    for (int s = 0; s < 4; s++) {
        unsigned short u = w[(threadIdx.x * 4 + s) * 2];
        float v = fabsf(u16bf(u));
        if (v > 1e-6f && v < 2.0f) hits++;
    }
    atomicAdd(&cnt, hits);
    __syncthreads();
    if (threadIdx.x == 0) *flag = (cnt > 512) ? 1 : 0;
}

// ---------------- conversions ----------------
// 13 bias segs + 2 zero segs (src=nullptr -> 0.f). grid (490, NSEG).
#define NSEG 15
struct CvtJob {
    const void* src[NSEG];
    float* dst[NSEG];
    int n[NSEG];
};

__global__ void megacvt(CvtJob job, const int* __restrict__ flagp) {
    int seg = blockIdx.y;
    int i = blockIdx.x * 256 + threadIdx.x;
    if (i >= job.n[seg]) return;
    const void* s = job.src[seg];
    if (s == nullptr) { job.dst[seg][i] = 0.f; return; }
    float v = (*flagp) ? b2f(((const bf16*)s)[i]) : ((const float*)s)[i];
    job.dst[seg][i] = v;
}

// embeddings -> bf16 (for conv1 MFMA gather staging)
__global__ void cvt_emb(const void* de, const void* pe, bf16* dB, bf16* pB,
                        const int* __restrict__ flagp) {
    int i = blockIdx.x * 256 + threadIdx.x;
    int f = *flagp;
    if (i < 65 * 64) {
        dB[i] = f ? ((const bf16*)de)[i] : __float2bfloat16(((const float*)de)[i]);
    } else if (i < 65 * 64 + 26 * 64) {
        int j = i - 65 * 64;
        pB[j] = f ? ((const bf16*)pe)[j] : __float2bfloat16(((const float*)pe)[j]);
    }
}

// all six conv-weight MFMA packs in one dispatch: [Cout][CIN][K] -> [k][coP][CIP]
__global__ void pack6(const void* s0, const void* s1, const void* s2,
                      const void* s3, const void* s4, const void* s5,
                      bf16* d0, bf16* d1, bf16* d2, bf16* d3, bf16* d4, bf16* d5,
                      const int* __restrict__ flagp) {
    int y = blockIdx.y;
    const void* src; bf16* dst; int Cout, CIN, K, coP, CIP;
    if (y == 0)      { src = s0; dst = d0; Cout = 40;  CIN = 64; K = 4;  coP = 48;  CIP = 64; }
    else if (y == 1) { src = s1; dst = d1; Cout = 40;  CIN = 64; K = 4;  coP = 48;  CIP = 64; }
    else if (y == 2) { src = s2; dst = d2; Cout = 80;  CIN = 40; K = 6;  coP = 128; CIP = 64; }
    else if (y == 3) { src = s3; dst = d3; Cout = 80;  CIN = 40; K = 8;  coP = 128; CIP = 64; }
    else if (y == 4) { src = s4; dst = d4; Cout = 160; CIN = 80; K = 8;  coP = 192; CIP = 96; }
    else             { src = s5; dst = d5; Cout = 160; CIN = 80; K = 12; coP = 192; CIP = 96; }
    int i = blockIdx.x * 256 + threadIdx.x;
    int total = K * coP * CIP;
    if (i >= total) return;
    int ci = i % CIP;
    int t = i / CIP;
    int co = t % coP;
    int k = t / coP;
    float v = 0.f;
    if (co < Cout && ci < CIN) {
        int s = (co * CIN + ci) * K + k;
        v = (*flagp) ? b2f(((const bf16*)src)[s]) : ((const float*)src)[s];
    }
    dst[i] = __float2bfloat16(v);
}

// [160,160] (o,c) -> bf16 [o][c] (A-operand layout), 3 matrices
__global__ void cvt160b(const void* s0, const void* s1, const void* s2,
                        bf16* d0, bf16* d1, bf16* d2, const int* __restrict__ flagp) {
    int i = blockIdx.x * 256 + threadIdx.x;
    if (i >= 25600) return;
    const void* s = blockIdx.y == 0 ? s0 : (blockIdx.y == 1 ? s1 : s2);
    bf16* d = blockIdx.y == 0 ? d0 : (blockIdx.y == 1 ? d1 : d2);
    float v = (*flagp) ? b2f(((const bf16*)s)[i]) : ((const float*)s)[i];
    d[i] = __float2bfloat16(v);
}

// ---------------- conv via MFMA implicit GEMM (R7-proven) ----------------
template <int K, int CIN, int CHUNKS>
__global__ __launch_bounds__(256) void conv_mfma(const bf16* __restrict__ x,
                                                 const bf16* __restrict__ Wp,
                                                 const float* __restrict__ bias,
                                                 bf16* __restrict__ y,
                                                 int Lin, int Lout, int Cout,
                                                 int coP, int tilesL) {
    const int CIP = CHUNKS * 32;
    const int PCI = CIP + 8;
    const int TLX = 64 + K - 1;
    __shared__ __align__(16) unsigned short xT[TLX * PCI];
    int b = blockIdx.x / tilesL;
    int l0 = (blockIdx.x % tilesL) << 6;
    const unsigned short* xb = (const unsigned short*)x + (size_t)b * CIN * Lin;
    for (int i = threadIdx.x; i < TLX * CIP; i += 256) {
        int ci = i / TLX, l = i - ci * TLX;
        unsigned short v = 0;
        int gl = l0 + l;
        if (ci < CIN && gl < Lin) v = xb[ci * Lin + gl];
        xT[l * PCI + ci] = v;
    }
    __syncthreads();
    int lane = threadIdx.x & 63;
    int w = threadIdx.x >> 6;
    int ct = blockIdx.y * 4 + w;
    int n = lane & 15, quad = lane >> 4;
    floatx4 acc[4];
#pragma unroll
    for (int i = 0; i < 4; i++) acc[i] = (floatx4){0.f, 0.f, 0.f, 0.f};
    const unsigned short* wbase = (const unsigned short*)Wp;
#pragma unroll
    for (int k = 0; k < K; k++) {
#pragma unroll
        for (int ch = 0; ch < CHUNKS; ch++) {
            short8 a = *(const short8*)(wbase +
                        ((size_t)(k * coP + ct * 16 + n)) * CIP + ch * 32 + quad * 8);
#pragma unroll
            for (int nt = 0; nt < 4; nt++) {
                short8 bb = *(const short8*)(xT + (nt * 16 + n + k) * PCI + ch * 32 + quad * 8);
                acc[nt] = __builtin_amdgcn_mfma_f32_16x16x32_bf16(a, bb, acc[nt], 0, 0, 0);
            }
        }
    }
    int m0 = quad * 4;
#pragma unroll
    for (int nt = 0; nt < 4; nt++) {
        int l = l0 + nt * 16 + n;
        if (l >= Lout) continue;
#pragma unroll
        for (int r = 0; r < 4; r++) {
            int co = ct * 16 + m0 + r;
            if (co < Cout)
                y[((size_t)b * Cout + co) * Lout + l] =
                    __float2bfloat16(fmaxf(acc[nt][r] + bias[co], 0.f));
        }
    }
}

// ---------------- conv1 via MFMA with embedding-gather staging (R10-proven) ----------------
__global__ __launch_bounds__(256) void conv1_mfma(const int* __restrict__ dtok,
                                                  const int* __restrict__ ptok,
                                                  const bf16* __restrict__ embDB,
                                                  const bf16* __restrict__ embPB,
                                                  const bf16* __restrict__ dW1p,
                                                  const bf16* __restrict__ pW1p,
                                                  const float* __restrict__ db1f,
                                                  const float* __restrict__ pb1f,
                                                  bf16* __restrict__ d1,
                                                  bf16* __restrict__ p1) {
    const int K = 4, CIP = 64, PCI = 72, TLX = 67, coP = 48, Cout = 40;
    __shared__ __align__(16) unsigned short xT[TLX * PCI];
    __shared__ int stok[TLX];
    bool isD = blockIdx.x < 16;
    int b, l0, Lin, Lout;
    const int* tok; const unsigned short* embB; const unsigned short* Wp;
    const float* bias; bf16* y;
    if (isD) {
        b = blockIdx.x; l0 = 0; Lin = 64; Lout = 61;
        tok = dtok; embB = (const unsigned short*)embDB;
        Wp = (const unsigned short*)dW1p; bias = db1f; y = d1;
    } else {
        int bx = blockIdx.x - 16;
        b = bx / 19; l0 = (bx % 19) << 6; Lin = 1200; Lout = 1197;
        tok = ptok; embB = (const unsigned short*)embPB;
        Wp = (const unsigned short*)pW1p; bias = pb1f; y = p1;
    }
    if (threadIdx.x < TLX) {
        int l = l0 + threadIdx.x;
        stok[threadIdx.x] = (l < Lin) ? tok[b * Lin + l] : -1;
    }
    __syncthreads();
    for (int i = threadIdx.x; i < TLX * CIP; i += 256) {
        int ci = i / TLX, l = i - ci * TLX;
        int t = stok[l];
        xT[l * PCI + ci] = (t >= 0) ? embB[t * 64 + ci] : (unsigned short)0;
    }
    __syncthreads();
    int lane = threadIdx.x & 63;
    int w = threadIdx.x >> 6;
    int n = lane & 15, quad = lane >> 4;
    if (w >= 3) return;
    floatx4 acc[4];
#pragma unroll
    for (int i = 0; i < 4; i++) acc[i] = (floatx4){0.f, 0.f, 0.f, 0.f};
#pragma unroll
    for (int k = 0; k < K; k++) {
#pragma unroll
        for (int ch = 0; ch < 2; ch++) {
            short8 a = *(const short8*)(Wp +
                        ((size_t)(k * coP + w * 16 + n)) * CIP + ch * 32 + quad * 8);
#pragma unroll
            for (int nt = 0; nt < 4; nt++) {
                short8 bb = *(const short8*)(xT + (nt * 16 + n + k) * PCI + ch * 32 + quad * 8);
                acc[nt] = __builtin_amdgcn_mfma_f32_16x16x32_bf16(a, bb, acc[nt], 0, 0, 0);
            }
        }
    }
    int m0 = quad * 4;
#pragma unroll
    for (int nt = 0; nt < 4; nt++) {
        int l = l0 + nt * 16 + n;
        if (l >= Lout) continue;
#pragma unroll
        for (int r = 0; r < 4; r++) {
            int co = w * 16 + m0 + r;
            if (co < Cout)
                y[((size_t)b * Cout + co) * Lout + l] =
                    __float2bfloat16(fmaxf(acc[nt][r] + bias[co], 0.f));
        }
    }
}

// ---------------- attention projection via MFMA (R8-proven) ----------------
__global__ __launch_bounds__(256) void att_proj_mfma(const bf16* __restrict__ dcB,
                                                     const bf16* __restrict__ pcB,
                                                     const bf16* __restrict__ dWB,
                                                     const bf16* __restrict__ pWB,
                                                     const float* __restrict__ dbF,
                                                     const float* __restrict__ pbF,
                                                     float* __restrict__ datt,
                                                     bf16* __restrict__ pattB) {
    const int PCI = 168;
    __shared__ __align__(16) unsigned short xT[64 * PCI];
    bool isD = blockIdx.x < 16;
    int b, l0, L;
    const unsigned short* xsrc; const unsigned short* W; const float* bias;
    if (isD) {
        b = blockIdx.x; l0 = 0; L = 49;
        xsrc = (const unsigned short*)dcB; W = (const unsigned short*)dWB; bias = dbF;
    } else {
        int bx = blockIdx.x - 16;
        b = bx / 19; l0 = (bx % 19) << 6; L = 1179;
        xsrc = (const unsigned short*)pcB; W = (const unsigned short*)pWB; bias = pbF;
    }
    const unsigned short* xb = xsrc + (size_t)b * 160 * L;
    for (int i = threadIdx.x; i < 160 * 64; i += 256) {
        int c = i >> 6, j = i & 63;
        int l = l0 + j;
        xT[j * PCI + c] = (l < L) ? xb[(size_t)c * L + l] : (unsigned short)0;
    }
    __syncthreads();
    int lane = threadIdx.x & 63;
    int w = threadIdx.x >> 6;
    int t = blockIdx.y * 4 + w;
    int n = lane & 15, quad = lane >> 4;
    if (t >= 10) return;
    floatx4 acc[4];
#pragma unroll
    for (int i = 0; i < 4; i++) acc[i] = (floatx4){0.f, 0.f, 0.f, 0.f};
#pragma unroll
    for (int ch = 0; ch < 5; ch++) {
        short8 a = *(const short8*)(W + ((size_t)(t * 16 + n)) * 160 + ch * 32 + quad * 8);
#pragma unroll
        for (int nt = 0; nt < 4; nt++) {
            short8 bb = *(const short8*)(xT + (nt * 16 + n) * PCI + ch * 32 + quad * 8);
            acc[nt] = __builtin_amdgcn_mfma_f32_16x16x32_bf16(a, bb, acc[nt], 0, 0, 0);
        }
    }
    int m0 = quad * 4;
    int o0 = t * 16 + m0;
#pragma unroll
    for (int nt = 0; nt < 4; nt++) {
        int l = l0 + nt * 16 + n;
        if (l >= L) continue;
        if (isD) {
            float4 v;
            v.x = acc[nt][0] + bias[o0 + 0];
            v.y = acc[nt][1] + bias[o0 + 1];
            v.z = acc[nt][2] + bias[o0 + 2];
            v.w = acc[nt][3] + bias[o0 + 3];
            *(float4*)(datt + ((size_t)b * 49 + l) * 160 + o0) = v;
        } else {
            ushort4 u;
            u.x = f2bu(acc[nt][0] + bias[o0 + 0]);
            u.y = f2bu(acc[nt][1] + bias[o0 + 1]);
            u.z = f2bu(acc[nt][2] + bias[o0 + 2]);
            u.w = f2bu(acc[nt][3] + bias[o0 + 3]);
            *(ushort4*)((unsigned short*)pattB + ((size_t)b * 1179 + l) * 160 + o0) = u;
        }
    }
}

// ---------------- fused means v3: d-outer, p-state in registers ----------------
// Live set: pv[32] + s[32] + scalars (~70 VGPR, no spill). One pass over patt.
// Invalid p -> pv=-1e30 -> relu==0 exactly (no Md contamination); skip Mp write.
__global__ __launch_bounds__(192) void mean_fused(const float* __restrict__ datt,
                                                  const bf16* __restrict__ patt,
                                                  bf16* __restrict__ MpW,
                                                  float* __restrict__ Md) {
    int k = threadIdx.x;
    if (k >= 160) return;
    int b = blockIdx.x / 37;
    int p0 = (blockIdx.x % 37) * 32;
    const unsigned short* pb = (const unsigned short*)patt + (size_t)b * 1179 * 160 + k;
    float pv[32], s[32];
#pragma unroll
    for (int pi = 0; pi < 32; pi++) {
        int p = p0 + pi;
        pv[pi] = (p < 1179) ? u16bf(pb[(size_t)p * 160]) : -1e30f;
        s[pi] = 0.f;
    }
    const float* drow = datt + (size_t)b * 49 * 160 + k;
    float* mdp = Md + (size_t)b * 49 * 160 + k;
    for (int d = 0; d < 49; d++) {
        float dv = drow[d * 160];
        float a0 = 0.f, a1 = 0.f, a2 = 0.f, a3 = 0.f;
#pragma unroll
        for (int g = 0; g < 8; g++) {
            float r0 = fmaxf(dv + pv[g * 4 + 0], 0.f);
            float r1 = fmaxf(dv + pv[g * 4 + 1], 0.f);
            float r2 = fmaxf(dv + pv[g * 4 + 2], 0.f);
            float r3 = fmaxf(dv + pv[g * 4 + 3], 0.f);
            s[g * 4 + 0] += r0; a0 += r0;
            s[g * 4 + 1] += r1; a1 += r1;
            s[g * 4 + 2] += r2; a2 += r2;
            s[g * 4 + 3] += r3; a3 += r3;
        }
        atomicAdd(mdp + d * 160, (a0 + a1) + (a2 + a3));
    }
#pragma unroll
    for (int pi = 0; pi < 32; pi++) {
        int p = p0 + pi;
        if (p < 1179)
            MpW[((size_t)b * 1184 + p) * 160 + k] = __float2bfloat16(s[pi] * (1.f / 49.f));
    }
}

// ---------------- att_sig via MFMA + fused sigmoid/scale/maxpool (R8-proven) ----------------
__global__ __launch_bounds__(256) void att_sig_mfma(const float* __restrict__ Md,
                                                    const bf16* __restrict__ MpW,
                                                    const bf16* __restrict__ wattB,
                                                    const float* __restrict__ attbF,
                                                    const bf16* __restrict__ dcB,
                                                    const bf16* __restrict__ pcB,
                                                    float* __restrict__ pair) {
    const int PCI = 168;
    __shared__ __align__(16) unsigned short sM[64 * PCI];
    bool isD = blockIdx.x < 16;
    int b, p0, L, off;
    const unsigned short* conv;
    if (isD) {
        b = blockIdx.x; p0 = 0; L = 49; off = 0; conv = (const unsigned short*)dcB;
        for (int i = threadIdx.x; i < 160 * 64; i += 256) {
            int r = i / 160, k = i - r * 160;
            float v = (r < 49) ? Md[((size_t)b * 49 + r) * 160 + k] * (1.f / 1179.f) : 0.f;
            sM[r * PCI + k] = f2bu(v);
        }
    } else {
        int bx = blockIdx.x - 16;
        b = bx / 19; p0 = (bx % 19) << 6; L = 1179; off = 160;
        conv = (const unsigned short*)pcB;
        const unsigned short* mb = (const unsigned short*)MpW + (size_t)b * 1184 * 160;
        for (int i = threadIdx.x; i < 160 * 64; i += 256) {
            int r = i / 160, k = i - r * 160;
            int p = p0 + r;
            sM[r * PCI + k] = (p < 1179) ? mb[(size_t)p * 160 + k] : (unsigned short)0;
        }
    }
    __syncthreads();
    int lane = threadIdx.x & 63;
    int w = threadIdx.x >> 6;
    int t = blockIdx.y * 4 + w;
    int n = lane & 15, quad = lane >> 4;
    if (t >= 10) return;
    floatx4 acc[4];
#pragma unroll
    for (int i = 0; i < 4; i++) acc[i] = (floatx4){0.f, 0.f, 0.f, 0.f};
    const unsigned short* W = (const unsigned short*)wattB;
#pragma unroll
    for (int ch = 0; ch < 5; ch++) {
        short8 a = *(const short8*)(W + ((size_t)(t * 16 + n)) * 160 + ch * 32 + quad * 8);
#pragma unroll
        for (int nt = 0; nt < 4; nt++) {
            short8 bb = *(const short8*)(sM + (nt * 16 + n) * PCI + ch * 32 + quad * 8);
            acc[nt] = __builtin_amdgcn_mfma_f32_16x16x32_bf16(a, bb, acc[nt], 0, 0, 0);
        }
    }
    int m0 = quad * 4;
    float vmax[4] = {0.f, 0.f, 0.f, 0.f};
#pragma unroll
    for (int nt = 0; nt < 4; nt++) {
        int p = p0 + nt * 16 + n;
#pragma unroll
        for (int r = 0; r < 4; r++) {
            int o = t * 16 + m0 + r;
            float sig = 1.f / (1.f + __expf(-(acc[nt][r] + attbF[o])));
            float v = 0.f;
            if (p < L) v = u16bf(conv[((size_t)b * 160 + o) * L + p]) * (0.5f + sig);
            vmax[r] = fmaxf(vmax[r], v);
        }
    }
#pragma unroll
    for (int m = 1; m < 16; m <<= 1) {
#pragma unroll
        for (int r = 0; r < 4; r++)
            vmax[r] = fmaxf(vmax[r], __shfl_xor(vmax[r], m, 64));
    }
    if (n == 0) {
#pragma unroll
        for (int r = 0; r < 4; r++)
            atomicMax((unsigned int*)(pair + b * 320 + off + t * 16 + m0 + r),
                      __float_as_uint(vmax[r]));
    }
}

// ---------------- MLP: block-per-output GEMV (R9-proven) ----------------
__global__ __launch_bounds__(256) void fc_block(const float* __restrict__ in,
                                                const void* __restrict__ W,
                                                const float* __restrict__ bias,
                                                float* __restrict__ out,
                                                int IN, int OUT,
                                                const int* __restrict__ flagp) {
    int j = blockIdx.x;
    int w = threadIdx.x >> 6, li = threadIdx.x & 63;
    int nv = IN >> 2;
    const float4* i0 = (const float4*)(in + (size_t)(w * 4 + 0) * IN);
    const float4* i1 = (const float4*)(in + (size_t)(w * 4 + 1) * IN);
    const float4* i2 = (const float4*)(in + (size_t)(w * 4 + 2) * IN);
    const float4* i3 = (const float4*)(in + (size_t)(w * 4 + 3) * IN);
    float p0 = 0.f, p1 = 0.f, p2 = 0.f, p3 = 0.f;
    if (*flagp) {
        const ushort4* w4 = (const ushort4*)((const unsigned short*)W + (size_t)j * IN);
        for (int v = li; v < nv; v += 64) {
            ushort4 u = w4[v];
            float wa = u16bf(u.x), wb = u16bf(u.y), wc = u16bf(u.z), wd = u16bf(u.w);
            float4 x;
            x = i0[v]; p0 += x.x * wa + x.y * wb + x.z * wc + x.w * wd;
            x = i1[v]; p1 += x.x * wa + x.y * wb + x.z * wc + x.w * wd;
            x = i2[v]; p2 += x.x * wa + x.y * wb + x.z * wc + x.w * wd;
            x = i3[v]; p3 += x.x * wa + x.y * wb + x.z * wc + x.w * wd;
        }
    } else {
        const float4* w4 = (const float4*)((const float*)W + (size_t)j * IN);
        for (int v = li; v < nv; v += 64) {
            float4 u = w4[v];
            float4 x;
            x = i0[v]; p0 += x.x * u.x + x.y * u.y + x.z * u.z + x.w * u.w;
            x = i1[v]; p1 += x.x * u.x + x.y * u.y + x.z * u.z + x.w * u.w;
            x = i2[v]; p2 += x.x * u.x + x.y * u.y + x.z * u.z + x.w * u.w;
            x = i3[v]; p3 += x.x * u.x + x.y * u.y + x.z * u.z + x.w * u.w;
        }
    }
#pragma unroll
    for (int m = 1; m < 64; m <<= 1) {
        p0 += __shfl_xor(p0, m, 64);
        p1 += __shfl_xor(p1, m, 64);
        p2 += __shfl_xor(p2, m, 64);
        p3 += __shfl_xor(p3, m, 64);
    }
    if (li == 0) {
        float bj = bias[j];
        float o0 = p0 + bj, o1 = p1 + bj, o2 = p2 + bj, o3 = p3 + bj;
        o0 = o0 > 0.f ? o0 : 0.01f * o0;
        o1 = o1 > 0.f ? o1 : 0.01f * o1;
        o2 = o2 > 0.f ? o2 : 0.01f * o2;
        o3 = o3 > 0.f ? o3 : 0.01f * o3;
        out[(size_t)(w * 4 + 0) * OUT + j] = o0;
        out[(size_t)(w * 4 + 1) * OUT + j] = o1;
        out[(size_t)(w * 4 + 2) * OUT + j] = o2;
        out[(size_t)(w * 4 + 3) * OUT + j] = o3;
    }
}

__global__ __launch_bounds__(256) void out_block(const float* __restrict__ h,
                                                 const void* __restrict__ W,
                                                 const float* __restrict__ biasF,
                                                 void* __restrict__ out,
                                                 const int* __restrict__ flagp) {
    int j = blockIdx.x;
    int w = threadIdx.x >> 6, li = threadIdx.x & 63;
    const int IN = 512, nv = 128;
    const float4* i0 = (const float4*)(h + (size_t)(w * 4 + 0) * IN);
    const float4* i1 = (const float4*)(h + (size_t)(w * 4 + 1) * IN);
    const float4* i2 = (const float4*)(h + (size_t)(w * 4 + 2) * IN);
    const float4* i3 = (const float4*)(h + (size_t)(w * 4 + 3) * IN);
    float p0 = 0.f, p1 = 0.f, p2 = 0.f, p3 = 0.f;
    int flag = *flagp;
    if (flag) {
        const ushort4* w4 = (const ushort4*)((const unsigned short*)W + (size_t)j * IN);
        for (int v = li; v < nv; v += 64) {
            ushort4 u = w4[v];
            float wa = u16bf(u.x), wb = u16bf(u.y), wc = u16bf(u.z), wd = u16bf(u.w);
            float4 x;
            x = i0[v]; p0 += x.x * wa + x.y * wb + x.z * wc + x.w * wd;
            x = i1[v]; p1 += x.x * wa + x.y * wb + x.z * wc + x.w * wd;
            x = i2[v]; p2 += x.x * wa + x.y * wb + x.z * wc + x.w * wd;
            x = i3[v]; p3 += x.x * wa + x.y * wb + x.z * wc + x.w * wd;
        }
    } else {
        const float4* w4 = (const float4*)((const float*)W + (size_t)j * IN);
        for (int v = li; v < nv; v += 64) {
            float4 u = w4[v];
            float4 x;
            x = i0[v]; p0 += x.x * u.x + x.y * u.y + x.z * u.z + x.w * u.w;
            x = i1[v]; p1 += x.x * u.x + x.y * u.y + x.z * u.z + x.w * u.w;
            x = i2[v]; p2 += x.x * u.x + x.y * u.y + x.z * u.z + x.w * u.w;
            x = i3[v]; p3 += x.x * u.x + x.y * u.y + x.z * u.z + x.w * u.w;
        }
    }
#pragma unroll
    for (int m = 1; m < 64; m <<= 1) {
        p0 += __shfl_xor(p0, m, 64);
        p1 += __shfl_xor(p1, m, 64);
        p2 += __shfl_xor(p2, m, 64);
        p3 += __shfl_xor(p3, m, 64);
    }
    if (li == 0) {
        float bj = biasF[j];
        float o0 = p0 + bj, o1 = p1 + bj, o2 = p2 + bj, o3 = p3 + bj;
        if (flag) {
            bf16* ob = (bf16*)out;
            ob[(w * 4 + 0) * 2 + j] = __float2bfloat16(o0);
            ob[(w * 4 + 1) * 2 + j] = __float2bfloat16(o1);
            ob[(w * 4 + 2) * 2 + j] = __float2bfloat16(o2);
            ob[(w * 4 + 3) * 2 + j] = __float2bfloat16(o3);
        } else {
            float* of = (float*)out;
            of[(w * 4 + 0) * 2 + j] = o0;
            of[(w * 4 + 1) * 2 + j] = o1;
            of[(w * 4 + 2) * 2 + j] = o2;
            of[(w * 4 + 3) * 2 + j] = o3;
        }
    }
}

extern "C" void kernel_launch(void* const* d_in, const int* in_sizes, int n_in,
                              void* d_out, int out_size, void* d_ws, size_t ws_size,
                              hipStream_t stream) {
    const int* drug_tok = (const int*)d_in[0];
    const int* prot_tok = (const int*)d_in[1];
    const void* drug_emb = d_in[2];
    const void* prot_emb = d_in[3];
    const void* dW1 = d_in[4];  const void* db1 = d_in[5];
    const void* dW2 = d_in[6];  const void* db2 = d_in[7];
    const void* dW3 = d_in[8];  const void* db3 = d_in[9];
    const void* pW1 = d_in[10]; const void* pb1 = d_in[11];
    const void* pW2 = d_in[12]; const void* pb2 = d_in[13];
    const void* pW3 = d_in[14]; const void* pb3 = d_in[15];
    const void* dattW = d_in[16]; const void* dattb = d_in[17];
    const void* pattW = d_in[18]; const void* pattb = d_in[19];
    const void* attW  = d_in[20]; const void* attb  = d_in[21];
    const void* fc1W = d_in[22]; const void* fc1b = d_in[23];
    const void* fc2W = d_in[24]; const void* fc2b = d_in[25];
    const void* fc3W = d_in[26]; const void* fc3b = d_in[27];
    const void* outW = d_in[28]; const void* outb = d_in[29];

    char* base = (char*)d_ws;
    size_t cur = 0;
    auto alloc = [&](size_t bytes) -> char* {
        char* p = base + cur;
        cur = (cur + bytes + 255) & ~(size_t)255;
        return p;
    };
    int*   flag  = (int*)alloc(256);
    bf16* embDB = (bf16*)alloc(65 * 64 * 2);
    bf16* embPB = (bf16*)alloc(26 * 64 * 2);
    bf16* dW1p = (bf16*)alloc((size_t)4 * 48 * 64 * 2);
    bf16* pW1p = (bf16*)alloc((size_t)4 * 48 * 64 * 2);
    bf16* dW2p = (bf16*)alloc((size_t)6 * 128 * 64 * 2);
    bf16* dW3p = (bf16*)alloc((size_t)8 * 192 * 96 * 2);
    bf16* pW2p = (bf16*)alloc((size_t)8 * 128 * 64 * 2);
    bf16* pW3p = (bf16*)alloc((size_t)12 * 192 * 96 * 2);
    float* db1f = (float*)alloc(40 * 4);
    float* db2f = (float*)alloc(80 * 4);
    float* db3f = (float*)alloc(160 * 4);
    float* pb1f = (float*)alloc(40 * 4);
    float* pb2f = (float*)alloc(80 * 4);
    float* pb3f = (float*)alloc(160 * 4);
    float* dattbF = (float*)alloc(160 * 4);
    float* pattbF = (float*)alloc(160 * 4);
    float* attbF  = (float*)alloc(160 * 4);
    float* fc1bF = (float*)alloc(1024 * 4);
    float* fc2bF = (float*)alloc(1024 * 4);
    float* fc3bF = (float*)alloc(512 * 4);
    float* outbF = (float*)alloc(2 * 4);
    bf16* dattWB = (bf16*)alloc(25600 * 2);
    bf16* pattWB = (bf16*)alloc(25600 * 2);
    bf16* wattB  = (bf16*)alloc(25600 * 2);
    bf16* d1  = (bf16*)alloc((size_t)NB * 40 * 61 * 2);
    bf16* d2  = (bf16*)alloc((size_t)NB * 80 * 56 * 2);
    bf16* dcB = (bf16*)alloc((size_t)NB * 160 * 49 * 2);
    bf16* p1  = (bf16*)alloc((size_t)NB * 40 * 1197 * 2);
    bf16* p2  = (bf16*)alloc((size_t)NB * 80 * 1190 * 2);
    bf16* pcB = (bf16*)alloc((size_t)NB * 160 * 1179 * 2);
    float* datt  = (float*)alloc((size_t)NB * 49 * 160 * 4);
    bf16* pattB = (bf16*)alloc((size_t)NB * 1179 * 160 * 2);
    float* Md   = (float*)alloc((size_t)NB * 49 * 160 * 4);
    bf16* MpW  = (bf16*)alloc((size_t)NB * 1184 * 160 * 2);
    float* pair = (float*)alloc(NB * 320 * 4);
    float* h1 = (float*)alloc(NB * 1024 * 4);
    float* h2 = (float*)alloc(NB * 1024 * 4);
    float* h3 = (float*)alloc(NB * 512 * 4);

    // 1) dtype sniff
    sniff_kernel<<<1, 256, 0, stream>>>((const unsigned short*)fc2W, flag);

    // 2) parameter conversion (13 bias segs + pair/Md zero segs)
    CvtJob job;
    int si = 0;
    auto add = [&](const void* s, float* d, int n) { job.src[si] = s; job.dst[si] = d; job.n[si] = n; si++; };
    add(db1, db1f, 40); add(db2, db2f, 80); add(db3, db3f, 160);
    add(pb1, pb1f, 40); add(pb2, pb2f, 80); add(pb3, pb3f, 160);
    add(dattb, dattbF, 160); add(pattb, pattbF, 160); add(attb, attbF, 160);
    add(fc1b, fc1bF, 1024); add(fc2b, fc2bF, 1024); add(fc3b, fc3bF, 512);
    add(outb, outbF, 2);
    add(nullptr, pair, NB * 320);
    add(nullptr, Md, NB * 49 * 160);
    megacvt<<<dim3(490, NSEG), 256, 0, stream>>>(job, flag);
    cvt_emb<<<23, 256, 0, stream>>>(drug_emb, prot_emb, embDB, embPB, flag);
    pack6<<<dim3(864, 6), 256, 0, stream>>>(dW1, pW1, dW2, pW2, dW3, pW3,
                                            dW1p, pW1p, dW2p, pW2p, dW3p, pW3p, flag);
    cvt160b<<<dim3(100, 3), 256, 0, stream>>>(dattW, pattW, attW, dattWB, pattWB, wattB, flag);

    // 3) CNN stacks: all MFMA
    conv1_mfma<<<16 + 16 * 19, 256, 0, stream>>>(drug_tok, prot_tok, embDB, embPB,
                                                 dW1p, pW1p, db1f, pb1f, d1, p1);
    conv_mfma<6, 40, 2><<<dim3(16, 2), 256, 0, stream>>>(d1, dW2p, db2f, d2, 61, 56, 80, 128, 1);
    conv_mfma<8, 40, 2><<<dim3(16 * 19, 2), 256, 0, stream>>>(p1, pW2p, pb2f, p2, 1197, 1190, 80, 128, 19);
    conv_mfma<8, 80, 3><<<dim3(16, 3), 256, 0, stream>>>(d2, dW3p, db3f, dcB, 56, 49, 160, 192, 1);
    conv_mfma<12, 80, 3><<<dim3(16 * 19, 3), 256, 0, stream>>>(p2, pW3p, pb3f, pcB, 1190, 1179, 160, 192, 19);

    // 4) attention projections (MFMA)
    att_proj_mfma<<<dim3(16 + 304, 3), 256, 0, stream>>>(dcB, pcB, dattWB, pattWB,
                                                         dattbF, pattbF, datt, pattB);

    // 5) fused pairwise relu-means (v3: d-outer, p-state registers)
    mean_fused<<<16 * 37, 192, 0, stream>>>(datt, pattB, MpW, Md);

    // 6) fused attW-GEMM + sigmoid + scale + maxpool (MFMA)
    att_sig_mfma<<<dim3(16 + 304, 3), 256, 0, stream>>>(Md, MpW, wattB, attbF, dcB, pcB, pair);

    // 7) MLP head (block-per-output GEMV)
    fc_block<<<1024, 256, 0, stream>>>(pair, fc1W, fc1bF, h1, 320, 1024, flag);
    fc_block<<<1024, 256, 0, stream>>>(h1, fc2W, fc2bF, h2, 1024, 1024, flag);
    fc_block<<<512, 256, 0, stream>>>(h2, fc3W, fc3bF, h3, 1024, 512, flag);
    out_block<<<2, 256, 0, stream>>>(h3, outW, outbF, d_out, flag);
}